// Round 11
// baseline (839.366 us; speedup 1.0000x reference)
//
#include <hip/hip_runtime.h>
#include <stdint.h>

typedef unsigned short u16;
typedef __bf16 bf16_t;
typedef bf16_t bf16x8 __attribute__((ext_vector_type(8)));
typedef float f32x4 __attribute__((ext_vector_type(4)));

// ---------- helpers ----------
__device__ __forceinline__ u16 f2b(float f) {
  union { float f; uint32_t u; } x; x.f = f;
  uint32_t r = x.u + 0x7fffu + ((x.u >> 16) & 1u);
  return (u16)(r >> 16);
}
__device__ __forceinline__ float b2f(u16 b) {
  union { uint32_t u; float f; } x; x.u = ((uint32_t)b) << 16;
  return x.f;
}

// async global->LDS, 16B per lane. LDS dest = wave-uniform base + lane*16.
__device__ __forceinline__ void async16(const void* g, void* l) {
  auto gp = reinterpret_cast<__attribute__((address_space(1))) unsigned int*>(
      reinterpret_cast<uintptr_t>(g));
  auto lp = reinterpret_cast<__attribute__((address_space(3))) unsigned int*>(
      reinterpret_cast<uintptr_t>(l));
  __builtin_amdgcn_global_load_lds(gp, lp, 16, 0, 0);
}

// ---------- gemm_bt body (3-buffer 2-deep prefetch, counted vmcnt) as device fn ----------
__device__ __forceinline__ void gemm_bt_body(
    const u16* __restrict__ A, const u16* __restrict__ B,
    const float* __restrict__ bias,
    const u16* __restrict__ residB, const float* __restrict__ residF,
    u16* __restrict__ Cb, float* __restrict__ Cf,
    int M, int N, int K, int ldA, int ldB, int ldC, int ldR,
    long aSH, long bSH, long cSH, long rSH, float alpha,
    int bx, int by, int bz, u16* sAll)
{
  const int tid = threadIdx.x;
  const int wave = tid >> 6, lane = tid & 63;
  const int lr = lane & 15, lg = lane >> 4;
  const int wm = wave >> 1, wn = wave & 1;
  const int z = bz;

  const u16* Ab = A + (long)z * aSH;
  const u16* Bb = B + (long)z * bSH;
  const int m0 = by * 128;
  const int n0 = bx * 128;

  const int srow = tid >> 2;
  const int sgk = (tid & 3) ^ ((tid >> 3) & 3);
  int ar0 = m0 + srow;      if (ar0 > M - 1) ar0 = M - 1;
  int ar1 = m0 + 64 + srow; if (ar1 > M - 1) ar1 = M - 1;
  int br0 = n0 + srow;      if (br0 > N - 1) br0 = N - 1;
  int br1 = n0 + 64 + srow; if (br1 > N - 1) br1 = N - 1;
  const u16* aP0 = Ab + (long)ar0 * ldA + sgk * 8;
  const u16* aP1 = Ab + (long)ar1 * ldA + sgk * 8;
  const u16* bP0 = Bb + (long)br0 * ldB + sgk * 8;
  const u16* bP1 = Bb + (long)br1 * ldB + sgk * 8;

  auto stage = [&](int buf, int k0) {
    u16* p = sAll + buf * 8192;
    async16(aP0 + k0, p + wave * 512);
    async16(aP1 + k0, p + 2048 + wave * 512);
    async16(bP0 + k0, p + 4096 + wave * 512);
    async16(bP1 + k0, p + 6144 + wave * 512);
  };

  const int swz = (lr >> 1) & 3;
  int aoff[4], boff[4];
#pragma unroll
  for (int i = 0; i < 4; ++i) {
    aoff[i] = (wm * 64 + i * 16 + lr) * 32 + ((lg ^ swz) * 8);
    boff[i] = (wn * 64 + i * 16 + lr) * 32 + ((lg ^ swz) * 8);
  }

  f32x4 acc[4][4] = {};
  const int kiters = K >> 5;

  stage(0, 0);
  if (kiters > 1) stage(1, 32);

  int cur = 0;
  for (int kt = 0; kt < kiters; ++kt) {
    if (kt + 2 < kiters) {
      const int nx = (cur + 2 >= 3) ? cur - 1 : cur + 2;
      stage(nx, (kt + 2) << 5);
    }
    if (kt + 2 < kiters)      asm volatile("s_waitcnt vmcnt(8)" ::: "memory");
    else if (kt + 1 < kiters) asm volatile("s_waitcnt vmcnt(4)" ::: "memory");
    else                      asm volatile("s_waitcnt vmcnt(0)" ::: "memory");
    __builtin_amdgcn_s_barrier();
    asm volatile("" ::: "memory");

    const u16* base = sAll + cur * 8192;
    bf16x8 af[4], bfr[4];
#pragma unroll
    for (int i = 0; i < 4; ++i) af[i] = *(const bf16x8*)(base + aoff[i]);
#pragma unroll
    for (int i = 0; i < 4; ++i) bfr[i] = *(const bf16x8*)(base + 4096 + boff[i]);
#pragma unroll
    for (int i = 0; i < 4; ++i)
#pragma unroll
      for (int j = 0; j < 4; ++j)
        acc[i][j] = __builtin_amdgcn_mfma_f32_16x16x32_bf16(af[i], bfr[j], acc[i][j], 0, 0, 0);

    asm volatile("" ::: "memory");
    __builtin_amdgcn_s_barrier();
    cur = (cur + 1 == 3) ? 0 : cur + 1;
  }

  // C/D layout: col = lane&15, row = (lane>>4)*4 + reg  [m89/m91]
  const long coff = (long)z * cSH;
  const long roff = (long)z * rSH;
#pragma unroll
  for (int j = 0; j < 4; ++j) {
    const int n = n0 + wn * 64 + j * 16 + lr;
    if (n < N) {
      const float bv = bias ? bias[n] : 0.0f;
#pragma unroll
      for (int i = 0; i < 4; ++i) {
        const int mb = m0 + wm * 64 + i * 16 + lg * 4;
#pragma unroll
        for (int r = 0; r < 4; ++r) {
          const int m = mb + r;
          float v = alpha * acc[i][j][r] + bv;
          const long ri = roff + (long)m * ldR + n;
          if (residB) v += b2f(residB[ri]);
          if (residF) v += residF[ri];
          const long ci = coff + (long)m * ldC + n;
          if (Cb) Cb[ci] = f2b(v);
          if (Cf) Cf[ci] = v;
        }
      }
    }
  }
}

// ---------- single-job gemm kernel ----------
__global__ __launch_bounds__(256) void pz_gemm_bt(
    const u16* __restrict__ A, const u16* __restrict__ B,
    const float* __restrict__ bias,
    const u16* __restrict__ residB, const float* __restrict__ residF,
    u16* __restrict__ Cb, float* __restrict__ Cf,
    int M, int N, int K, int ldA, int ldB, int ldC, int ldR,
    long aSH, long bSH, long cSH, long rSH, float alpha)
{
  __shared__ __align__(16) u16 sAll[3 * 8192];
  gemm_bt_body(A, B, bias, residB, residF, Cb, Cf, M, N, K, ldA, ldB, ldC, ldR,
               aSH, bSH, cSH, rSH, alpha, blockIdx.x, blockIdx.y, blockIdx.z, sAll);
}

// ---------- dual-job gemm kernel: blockIdx.y < split -> job0, else job1 ----------
__global__ __launch_bounds__(256) void pz_gemm_bt2(
    const u16* A0, const u16* B0, const float* bias0,
    const u16* rB0, const float* rF0, u16* Cb0, float* Cf0,
    int M0, int N0, int K0, int ldA0, int ldB0, int ldC0, int ldR0, float alpha0,
    const u16* A1, const u16* B1, const float* bias1,
    const u16* rB1, const float* rF1, u16* Cb1, float* Cf1,
    int M1, int N1, int K1, int ldA1, int ldB1, int ldC1, int ldR1, float alpha1,
    int split)
{
  __shared__ __align__(16) u16 sAll[3 * 8192];
  if ((int)blockIdx.y < split)
    gemm_bt_body(A0, B0, bias0, rB0, rF0, Cb0, Cf0, M0, N0, K0, ldA0, ldB0, ldC0, ldR0,
                 0, 0, 0, 0, alpha0, blockIdx.x, blockIdx.y, 0, sAll);
  else
    gemm_bt_body(A1, B1, bias1, rB1, rF1, Cb1, Cf1, M1, N1, K1, ldA1, ldB1, ldC1, ldR1,
                 0, 0, 0, 0, alpha1, blockIdx.x, blockIdx.y - split, 0, sAll);
}

// ---------- merged fused attention: spatial (x<128) + temporal flash (x>=128) ----------
// grid (144, 1, 32): z -> (batch = z>>3, head = z&7).
__global__ __launch_bounds__(256) void pz_attn(
    const u16* __restrict__ Qs, const u16* __restrict__ Ks,
    const u16* __restrict__ Vs, u16* __restrict__ Os,
    const u16* __restrict__ Qt, const u16* __restrict__ Kt,
    const u16* __restrict__ VTt, u16* __restrict__ Ot,
    int ldQ, int ldK)
{
  __shared__ __align__(16) u16 sQ[32 * 64];
  __shared__ __align__(16) u16 sK[512 * 32];
  __shared__ float redm[32][4];
  __shared__ float reds[32][4];
  __shared__ float m_run[32], l_run[32], alpha_sh[32];

  const int tid = threadIdx.x;
  const int wave = tid >> 6, lane = tid & 63;
  const int lr = lane & 15, lg = lane >> 4;
  const int z = blockIdx.z;
  const int b = z >> 3, h = z & 7;

  if (blockIdx.x < 128) {
    // ================= spatial attention =================
    const int q0 = blockIdx.x * 32;
    const u16* Qb = Qs + (long)b * 4096 * ldQ + h * 64;
    const u16* Kb = Ks + (long)b * 512 * ldK + h * 64;
    const u16* Vb = Vs + ((long)b * 8 + h) * (64L * 512);
    u16* Ob = Os + (long)b * 4096 * 512 + h * 64;

    {
      const int qrow = wave * 8 + (lane >> 3);
      const int qcol = ((lane & 7) ^ (lane >> 3)) * 8;
      async16(Qb + (long)(q0 + qrow) * ldQ + qcol, sQ + wave * 512);
    }
    const int krow = wave * 16 + (lane >> 2);
    const int kcol = ((lane & 3) ^ ((lane >> 3) & 3)) * 8;
    const u16* kP = Kb + (long)krow * ldK + kcol;

    f32x4 acc[8][2] = {};
#pragma unroll
    for (int kk = 0; kk < 2; ++kk) {
      __syncthreads();
#pragma unroll
      for (int s = 0; s < 8; ++s)
        async16(kP + kk * 32 + (long)s * 64 * ldK, sK + s * 2048 + wave * 512);
      __builtin_amdgcn_s_waitcnt(0x0f70);
      __syncthreads();

      bf16x8 kf[8], qf[2];
#pragma unroll
      for (int kb = 0; kb < 8; ++kb) {
        const int n = wave * 128 + kb * 16 + lr;
        kf[kb] = *(const bf16x8*)(sK + n * 32 + ((lg ^ ((lr >> 1) & 3)) * 8));
      }
#pragma unroll
      for (int nq = 0; nq < 2; ++nq) {
        const int r = nq * 16 + lr;
        qf[nq] = *(const bf16x8*)(sQ + r * 64 + (((kk * 4 + lg) ^ (r & 7)) * 8));
      }
      __builtin_amdgcn_s_setprio(1);
#pragma unroll
      for (int kb = 0; kb < 8; ++kb)
#pragma unroll
        for (int nq = 0; nq < 2; ++nq)
          acc[kb][nq] = __builtin_amdgcn_mfma_f32_16x16x32_bf16(kf[kb], qf[nq], acc[kb][nq], 0, 0, 0);
      __builtin_amdgcn_s_setprio(0);
    }

    float mx0, mx1;
    {
      float m0 = acc[0][0][0], m1 = acc[0][1][0];
#pragma unroll
      for (int kb = 0; kb < 8; ++kb)
#pragma unroll
        for (int rg = 0; rg < 4; ++rg) {
          m0 = fmaxf(m0, acc[kb][0][rg]);
          m1 = fmaxf(m1, acc[kb][1][rg]);
        }
      m0 = fmaxf(m0, __shfl_xor(m0, 16, 64)); m0 = fmaxf(m0, __shfl_xor(m0, 32, 64));
      m1 = fmaxf(m1, __shfl_xor(m1, 16, 64)); m1 = fmaxf(m1, __shfl_xor(m1, 32, 64));
      mx0 = m0; mx1 = m1;
    }
    if (lane < 16) { redm[lr][wave] = mx0; redm[16 + lr][wave] = mx1; }
    __syncthreads();
    float inv[2];
#pragma unroll
    for (int nq = 0; nq < 2; ++nq) {
      const int q = nq * 16 + lr;
      const float m = fmaxf(fmaxf(redm[q][0], redm[q][1]), fmaxf(redm[q][2], redm[q][3]));
      float s = 0.0f;
#pragma unroll
      for (int kb = 0; kb < 8; ++kb)
#pragma unroll
        for (int rg = 0; rg < 4; ++rg) {
          const float e = __expf(0.125f * (acc[kb][nq][rg] - m));
          acc[kb][nq][rg] = e;
          s += e;
        }
      s += __shfl_xor(s, 16, 64);
      s += __shfl_xor(s, 32, 64);
      if (lane < 16) reds[q][wave] = s;
    }
    __syncthreads();
#pragma unroll
    for (int nq = 0; nq < 2; ++nq) {
      const int q = nq * 16 + lr;
      inv[nq] = 1.0f / (reds[q][0] + reds[q][1] + reds[q][2] + reds[q][3]);
    }

#pragma unroll
    for (int nq = 0; nq < 2; ++nq) {
      const int q = nq * 16 + lr;
#pragma unroll
      for (int kb = 0; kb < 8; ++kb) {
        ushort4 w;
        w.x = f2b(acc[kb][nq][0] * inv[nq]);
        w.y = f2b(acc[kb][nq][1] * inv[nq]);
        w.z = f2b(acc[kb][nq][2] * inv[nq]);
        w.w = f2b(acc[kb][nq][3] * inv[nq]);
        const int c16 = wave * 16 + kb * 2 + (lg >> 1);
        const int byteoff = q * 1024 + ((c16 ^ (q & 7)) * 16) + (lg & 1) * 8;
        *(ushort4*)((char*)sK + byteoff) = w;
      }
    }
    __syncthreads();

    const u16* vp = Vb + (long)(wave * 16 + lr) * 512;
    f32x4 opv[2] = {};
#pragma unroll
    for (int ks = 0; ks < 16; ++ks) {
      const bf16x8 bv = *(const bf16x8*)(vp + ks * 32 + lg * 8);
      bf16x8 pf[2];
#pragma unroll
      for (int mi = 0; mi < 2; ++mi) {
        const int r = mi * 16 + lr;
        pf[mi] = *(const bf16x8*)((char*)sK + r * 1024 + (((ks * 4 + lg) ^ (lr & 7)) * 16));
      }
      __builtin_amdgcn_s_setprio(1);
#pragma unroll
      for (int mi = 0; mi < 2; ++mi)
        opv[mi] = __builtin_amdgcn_mfma_f32_16x16x32_bf16(pf[mi], bv, opv[mi], 0, 0, 0);
      __builtin_amdgcn_s_setprio(0);
    }
#pragma unroll
    for (int mi = 0; mi < 2; ++mi)
#pragma unroll
      for (int rg = 0; rg < 4; ++rg) {
        const int q = q0 + mi * 16 + lg * 4 + rg;
        Ob[(long)q * 512 + wave * 16 + lr] = f2b(opv[mi][rg]);
      }
  } else {
    // ================= temporal flash attention =================
    const int q0 = (blockIdx.x - 128) * 32;
    const u16* Qb = Qt + (long)b * 512 * ldQ + h * 64;
    const u16* Kb = Kt + (long)b * 4096 * ldK + h * 64;
    const u16* Vb = VTt + (long)b * 512 * 4096 + (long)h * 64 * 4096;
    u16* Ob = Ot + (long)b * 512 * 512 + h * 64;

    if (tid < 32) { m_run[tid] = -3.0e38f; l_run[tid] = 0.0f; }

    {
      const int qrow = wave * 8 + (lane >> 3);
      const int qcol = ((lane & 7) ^ (lane >> 3)) * 8;
      async16(Qb + (long)(q0 + qrow) * ldQ + qcol, sQ + wave * 512);
    }
    const int krow = wave * 16 + (lane >> 2);
    const int kcol = ((lane & 3) ^ ((lane >> 3) & 3)) * 8;

    f32x4 opv[2] = {};

    for (int kt = 0; kt < 8; ++kt) {
      const u16* kP = Kb + ((long)kt * 512 + krow) * ldK + kcol;
      f32x4 acc[8][2] = {};
#pragma unroll
      for (int kk = 0; kk < 2; ++kk) {
        __syncthreads();   // protects sK rewrite vs previous tile's PV reads
#pragma unroll
        for (int s = 0; s < 8; ++s)
          async16(kP + kk * 32 + (long)s * 64 * ldK, sK + s * 2048 + wave * 512);
        __builtin_amdgcn_s_waitcnt(0x0f70);  // vmcnt(0)
        __syncthreads();

        bf16x8 kf[8], qf[2];
#pragma unroll
        for (int kb = 0; kb < 8; ++kb) {
          const int n = wave * 128 + kb * 16 + lr;
          kf[kb] = *(const bf16x8*)(sK + n * 32 + ((lg ^ ((lr >> 1) & 3)) * 8));
        }
#pragma unroll
        for (int nq = 0; nq < 2; ++nq) {
          const int r = nq * 16 + lr;
          qf[nq] = *(const bf16x8*)(sQ + r * 64 + (((kk * 4 + lg) ^ (r & 7)) * 8));
        }
        __builtin_amdgcn_s_setprio(1);
#pragma unroll
        for (int kb = 0; kb < 8; ++kb)
#pragma unroll
          for (int nq = 0; nq < 2; ++nq)
            acc[kb][nq] = __builtin_amdgcn_mfma_f32_16x16x32_bf16(kf[kb], qf[nq], acc[kb][nq], 0, 0, 0);
        __builtin_amdgcn_s_setprio(0);
      }

#pragma unroll
      for (int nq = 0; nq < 2; ++nq) {
        float m = acc[0][nq][0];
#pragma unroll
        for (int kb = 0; kb < 8; ++kb)
#pragma unroll
          for (int rg = 0; rg < 4; ++rg) m = fmaxf(m, acc[kb][nq][rg]);
        m = fmaxf(m, __shfl_xor(m, 16, 64));
        m = fmaxf(m, __shfl_xor(m, 32, 64));
        if (lane < 16) redm[nq * 16 + lr][wave] = m;
      }
      __syncthreads();

#pragma unroll
      for (int nq = 0; nq < 2; ++nq) {
        const int q = nq * 16 + lr;
        const float mt = fmaxf(fmaxf(redm[q][0], redm[q][1]), fmaxf(redm[q][2], redm[q][3]));
        const float mn = fmaxf(m_run[q], mt);
        float s = 0.0f;
#pragma unroll
        for (int kb = 0; kb < 8; ++kb)
#pragma unroll
          for (int rg = 0; rg < 4; ++rg) {
            const float e = __expf(0.125f * (acc[kb][nq][rg] - mn));
            acc[kb][nq][rg] = e;
            s += e;
          }
        s += __shfl_xor(s, 16, 64);
        s += __shfl_xor(s, 32, 64);
        if (lane < 16) reds[q][wave] = s;
      }
      __syncthreads();

      if (tid < 32) {
        const int q = tid;
        const float mt = fmaxf(fmaxf(redm[q][0], redm[q][1]), fmaxf(redm[q][2], redm[q][3]));
        const float mo = m_run[q];
        const float mn = fmaxf(mo, mt);
        const float al = __expf(0.125f * (mo - mn));
        l_run[q] = l_run[q] * al + (reds[q][0] + reds[q][1] + reds[q][2] + reds[q][3]);
        m_run[q] = mn;
        alpha_sh[q] = al;
      }
#pragma unroll
      for (int nq = 0; nq < 2; ++nq) {
        const int q = nq * 16 + lr;
#pragma unroll
        for (int kb = 0; kb < 8; ++kb) {
          ushort4 w;
          w.x = f2b(acc[kb][nq][0]);
          w.y = f2b(acc[kb][nq][1]);
          w.z = f2b(acc[kb][nq][2]);
          w.w = f2b(acc[kb][nq][3]);
          const int c16 = wave * 16 + kb * 2 + (lg >> 1);
          const int byteoff = q * 1024 + ((c16 ^ (q & 7)) * 16) + (lg & 1) * 8;
          *(ushort4*)((char*)sK + byteoff) = w;
        }
      }
      __syncthreads();

#pragma unroll
      for (int mi = 0; mi < 2; ++mi)
#pragma unroll
        for (int rg = 0; rg < 4; ++rg)
          opv[mi][rg] *= alpha_sh[mi * 16 + lg * 4 + rg];

      const u16* vp = Vb + (long)(wave * 16 + lr) * 4096 + kt * 512;
#pragma unroll
      for (int ks = 0; ks < 16; ++ks) {
        const bf16x8 bv = *(const bf16x8*)(vp + ks * 32 + lg * 8);
        bf16x8 pf[2];
#pragma unroll
        for (int mi = 0; mi < 2; ++mi) {
          const int r = mi * 16 + lr;
          pf[mi] = *(const bf16x8*)((char*)sK + r * 1024 + (((ks * 4 + lg) ^ (lr & 7)) * 16));
        }
        __builtin_amdgcn_s_setprio(1);
#pragma unroll
        for (int mi = 0; mi < 2; ++mi)
          opv[mi] = __builtin_amdgcn_mfma_f32_16x16x32_bf16(pf[mi], bv, opv[mi], 0, 0, 0);
        __builtin_amdgcn_s_setprio(0);
      }
    }

#pragma unroll
    for (int mi = 0; mi < 2; ++mi)
#pragma unroll
      for (int rg = 0; rg < 4; ++rg) {
        const int qr = mi * 16 + lg * 4 + rg;
        Ob[(long)(q0 + qr) * 512 + wave * 16 + lr] = f2b(opv[mi][rg] * (1.0f / l_run[qr]));
      }
  }
}

// ---------- fused dual GEMM + SwiGLU gate, 3-buffer 2-deep prefetch, counted vmcnt ----------
__global__ __launch_bounds__(256) void pz_gemm_uvgate(
    const u16* __restrict__ A, const u16* __restrict__ Bu, const u16* __restrict__ Bv,
    const float* __restrict__ biasU, const float* __restrict__ biasV,
    u16* __restrict__ G, int M, int N, int K, int ldA, int ldB, int ldG, int Npad)
{
  __shared__ __align__(16) u16 sAll[3 * 8192];   // 48 KB

  const int tid = threadIdx.x;
  const int wave = tid >> 6, lane = tid & 63;
  const int lr = lane & 15, lg = lane >> 4;
  const int wm = wave >> 1, wn = wave & 1;
  const int m0 = blockIdx.y * 128;
  const int n0 = blockIdx.x * 64;

  const int srow = tid >> 2;                      // 0..63
  const int sgk = (tid & 3) ^ ((tid >> 3) & 3);
  int ar0 = m0 + srow;      if (ar0 > M - 1) ar0 = M - 1;
  int ar1 = m0 + 64 + srow; if (ar1 > M - 1) ar1 = M - 1;
  int br  = n0 + srow;      if (br  > N - 1) br  = N - 1;
  const u16* aP0 = A + (long)ar0 * ldA + sgk * 8;
  const u16* aP1 = A + (long)ar1 * ldA + sgk * 8;
  const u16* uP  = Bu + (long)br * ldB + sgk * 8;
  const u16* vP  = Bv + (long)br * ldB + sgk * 8;

  auto stage = [&](int buf, int k0) {
    u16* b = sAll + buf * 8192;
    async16(aP0 + k0, b + wave * 512);
    async16(aP1 + k0, b + 2048 + wave * 512);
    async16(uP + k0, b + 4096 + wave * 512);
    async16(vP + k0, b + 6144 + wave * 512);
  };

  const int swz = (lr >> 1) & 3;
  int aoff[4], boff[2];
#pragma unroll
  for (int i = 0; i < 4; ++i) aoff[i] = (wm * 64 + i * 16 + lr) * 32 + ((lg ^ swz) * 8);
#pragma unroll
  for (int j = 0; j < 2; ++j) boff[j] = (wn * 32 + j * 16 + lr) * 32 + ((lg ^ swz) * 8);

  f32x4 aU[4][2] = {}, aV[4][2] = {};
  const int kiters = K >> 5;

  stage(0, 0);
  if (kiters > 1) stage(1, 32);

  int cur = 0;
  for (int kt = 0; kt < kiters; ++kt) {
    if (kt + 2 < kiters) {
      const int nx = (cur + 2 >= 3) ? cur - 1 : cur + 2;
      stage(nx, (kt + 2) << 5);
    }
    if (kt + 2 < kiters)      asm volatile("s_waitcnt vmcnt(8)" ::: "memory");
    else if (kt + 1 < kiters) asm volatile("s_waitcnt vmcnt(4)" ::: "memory");
    else                      asm volatile("s_waitcnt vmcnt(0)" ::: "memory");
    __builtin_amdgcn_s_barrier();            // all waves' tile-kt data visible
    asm volatile("" ::: "memory");

    const u16* base = sAll + cur * 8192;
    bf16x8 af[4], uf[2], vf[2];
#pragma unroll
    for (int i = 0; i < 4; ++i) af[i] = *(const bf16x8*)(base + aoff[i]);
#pragma unroll
    for (int j = 0; j < 2; ++j) uf[j] = *(const bf16x8*)(base + 4096 + boff[j]);
#pragma unroll
    for (int j = 0; j < 2; ++j) vf[j] = *(const bf16x8*)(base + 6144 + boff[j]);
#pragma unroll
    for (int i = 0; i < 4; ++i)
#pragma unroll
      for (int j = 0; j < 2; ++j) {
        aU[i][j] = __builtin_amdgcn_mfma_f32_16x16x32_bf16(af[i], uf[j], aU[i][j], 0, 0, 0);
        aV[i][j] = __builtin_amdgcn_mfma_f32_16x16x32_bf16(af[i], vf[j], aV[i][j], 0, 0, 0);
      }

    asm volatile("" ::: "memory");
    __builtin_amdgcn_s_barrier();            // all waves done reading buf cur
    cur = (cur + 1 == 3) ? 0 : cur + 1;
  }

#pragma unroll
  for (int j = 0; j < 2; ++j) {
    const int n = n0 + wn * 32 + j * 16 + lr;
    if (n < N) {
      const float bu = biasU[n], bv = biasV[n];
#pragma unroll
      for (int i = 0; i < 4; ++i) {
        const int mb = m0 + wm * 64 + i * 16 + lg * 4;
#pragma unroll
        for (int r = 0; r < 4; ++r) {
          const float u = aU[i][j][r] + bu;
          const float v = aV[i][j][r] + bv;
          G[(long)(mb + r) * ldG + n] = f2b((u / (1.0f + __expf(-u))) * v);
        }
      }
    } else if (n < Npad) {
#pragma unroll
      for (int i = 0; i < 4; ++i) {
        const int mb = m0 + wm * 64 + i * 16 + lg * 4;
#pragma unroll
        for (int r = 0; r < 4; ++r) G[(long)(mb + r) * ldG + n] = 0;
      }
    }
  }
}

// ---------- merged LN (spatial + temporal): rows [0,split) from X0, rest X1 ----------
__global__ __launch_bounds__(256) void pz_ln2(
    const float* __restrict__ X0, const float* __restrict__ X1,
    u16* __restrict__ O0, u16* __restrict__ O1, int split)
{
  __shared__ float sm[4], sq[4];
  const int tid = threadIdx.x;
  const long row = blockIdx.x;
  const float* x;
  u16* O;
  if (row < split) { x = X0 + row * 512; O = O0 + row * 512; }
  else             { const long r2 = row - split; x = X1 + r2 * 512; O = O1 + r2 * 512; }
  float a = x[tid], b = x[tid + 256];
  float s = a + b, q = a * a + b * b;
#pragma unroll
  for (int m = 32; m >= 1; m >>= 1) { s += __shfl_xor(s, m, 64); q += __shfl_xor(q, m, 64); }
  if ((tid & 63) == 0) { sm[tid >> 6] = s; sq[tid >> 6] = q; }
  __syncthreads();
  s = sm[0] + sm[1] + sm[2] + sm[3];
  q = sq[0] + sq[1] + sq[2] + sq[3];
  const float mean = s * (1.0f / 512.0f);
  const float rstd = rsqrtf(q * (1.0f / 512.0f) - mean * mean + 1e-5f);
  O[tid]       = f2b((a - mean) * rstd);
  O[tid + 256] = f2b((b - mean) * rstd);
}

// ---------- mix LN over concat(sctx[512] bf16, tmean[512] f32) + mix_Win f2b tail ----------
__global__ __launch_bounds__(256) void pz_mix_ln_f2b(
    const u16* __restrict__ SC, const float* __restrict__ TM,
    const float* __restrict__ g, const float* __restrict__ b, u16* __restrict__ H,
    const float* __restrict__ Wsrc, u16* __restrict__ Wdst)
{
  __shared__ float sm[4], sq[4];
  const int tid = threadIdx.x;
  if (blockIdx.x >= 16384) {
    const int i = (blockIdx.x - 16384) * 256 + tid;  // covers 5460*1024 exactly
    Wdst[i] = f2b(Wsrc[i]);
    return;
  }
  const long row = blockIdx.x;
  const int bb = (int)(row >> 12);
  const u16* x0 = SC + row * 512;
  const float* x1 = TM + (long)bb * 512;
  float v0 = b2f(x0[tid]), v1 = b2f(x0[tid + 256]);
  float v2 = x1[tid], v3 = x1[tid + 256];
  float s = v0 + v1 + v2 + v3;
  float q = v0 * v0 + v1 * v1 + v2 * v2 + v3 * v3;
#pragma unroll
  for (int m = 32; m >= 1; m >>= 1) { s += __shfl_xor(s, m, 64); q += __shfl_xor(q, m, 64); }
  if ((tid & 63) == 0) { sm[tid >> 6] = s; sq[tid >> 6] = q; }
  __syncthreads();
  s = sm[0] + sm[1] + sm[2] + sm[3];
  q = sq[0] + sq[1] + sq[2] + sq[3];
  const float mean = s * (1.0f / 1024.0f);
  const float rstd = rsqrtf(q * (1.0f / 1024.0f) - mean * mean + 1e-5f);
  u16* hr = H + row * 1024;
  hr[tid]       = f2b((v0 - mean) * rstd * g[tid]       + b[tid]);
  hr[tid + 256] = f2b((v1 - mean) * rstd * g[tid + 256] + b[tid + 256]);
  hr[tid + 512] = f2b((v2 - mean) * rstd * g[tid + 512] + b[tid + 512]);
  hr[tid + 768] = f2b((v3 - mean) * rstd * g[tid + 768] + b[tid + 768]);
}

// ---------- merged bf16 slice transpose: x<splitX -> job0, else job1 ----------
__global__ __launch_bounds__(256) void pz_transpose2(
    const u16* S0, u16* D0, int Nk0, int ldS0, int cb0, long sBS0, long dBS0,
    const u16* S1, u16* D1, int Nk1, int ldS1, int cb1, long sBS1, long dBS1,
    int splitX)
{
  __shared__ u16 t[64][65];
  const int tid = threadIdx.x;
  const int z = blockIdx.z;
  const u16* S; u16* D; int Nk, ldS, cb, nk0;
  if ((int)blockIdx.x < splitX) {
    S = S0 + (long)blockIdx.y * sBS0; D = D0 + (long)blockIdx.y * dBS0;
    Nk = Nk0; ldS = ldS0; cb = cb0; nk0 = blockIdx.x * 64;
  } else {
    S = S1 + (long)blockIdx.y * sBS1; D = D1 + (long)blockIdx.y * dBS1;
    Nk = Nk1; ldS = ldS1; cb = cb1; nk0 = (blockIdx.x - splitX) * 64;
  }
  for (int i = tid; i < 4096; i += 256) {
    int r = i >> 6, d = i & 63;
    t[r][d] = S[(long)(nk0 + r) * ldS + cb + z * 64 + d];
  }
  __syncthreads();
  for (int i = tid; i < 4096; i += 256) {
    int d = i >> 6, c = i & 63;
    D[((long)z * 64 + d) * Nk + nk0 + c] = t[c][d];
  }
}

// ---------- f32 transpose + convert to bf16, batched over two sources (Wo^T s/t) ----------
__global__ __launch_bounds__(256) void pz_transpose_f2b(
    const float* __restrict__ S0, const float* __restrict__ S1,
    u16* __restrict__ D, int Nk, int ldS, long dBS)
{
  __shared__ u16 t[64][65];
  const float* S = blockIdx.y ? S1 : S0;
  D += (long)blockIdx.y * dBS;
  const int z = blockIdx.z;
  const int nk0 = blockIdx.x * 64;
  const int tid = threadIdx.x;
  for (int i = tid; i < 4096; i += 256) {
    int r = i >> 6, d = i & 63;
    t[r][d] = f2b(S[(long)(nk0 + r) * ldS + z * 64 + d]);
  }
  __syncthreads();
  for (int i = tid; i < 4096; i += 256) {
    int d = i >> 6, c = i & 63;
    D[((long)z * 64 + d) * Nk + nk0 + c] = t[c][d];
  }
}

// ---------- f32 -> bf16 convert, two sources into one contiguous dest ----------
__global__ __launch_bounds__(256) void pz_f2b2(
    const float* __restrict__ s0, const float* __restrict__ s1, u16* __restrict__ d, int n)
{
  const int i = blockIdx.x * 256 + threadIdx.x;   // grid covers 2n exactly
  d[i] = (i < n) ? f2b(s0[i]) : f2b(s1[i - n]);
}

// ---------- merged precompute: fold Wqkv (id<3072) | fold bc (id<4096) | pad Wout ----------
__global__ __launch_bounds__(256) void pz_prep(
    const float* __restrict__ Ws, const float* __restrict__ Wt,
    const float* __restrict__ bs, const float* __restrict__ bt,
    const float* s_qg, const float* s_qb, const float* s_kg, const float* s_kb,
    const float* t_qg, const float* t_qb, const float* t_kg, const float* t_kb,
    u16* __restrict__ wA, u16* __restrict__ wB, float* bA, float* bB,
    const float* sWp, const float* s_bo, const float* s_bp,
    const float* tWp, const float* t_bo, const float* t_bp, float* bcs, float* bct,
    const float* __restrict__ Wout, u16* __restrict__ Dout)
{
  __shared__ float sb[4];
  const int id = blockIdx.x;
  if (id < 3072) {
    const int mat = (id >= 1536) ? 1 : 0;
    const int r = id - mat * 1536;
    const float* W = mat ? Wt : Ws;
    const float* bq = mat ? bt : bs;
    const float *g, *bl;
    if (!mat) { g = (r < 512) ? s_qg : s_kg; bl = (r < 512) ? s_qb : s_kb; }
    else      { g = (r < 512) ? t_qg : t_kg; bl = (r < 512) ? t_qb : t_kb; }
    const bool toA = (mat == 0) == (r < 512);
    u16* Wo_ = toA ? wA : wB;
    float* bo_ = toA ? bA : bB;
    float dot = 0.0f;
    for (int c = threadIdx.x; c < 512; c += 256) {
      float w = W[(long)r * 512 + c];
      Wo_[(long)r * 512 + c] = f2b(w * g[c]);
      dot += w * bl[c];
    }
#pragma unroll
    for (int m = 32; m >= 1; m >>= 1) dot += __shfl_xor(dot, m, 64);
    if ((threadIdx.x & 63) == 0) sb[threadIdx.x >> 6] = dot;
    __syncthreads();
    if (threadIdx.x == 0) bo_[r] = sb[0] + sb[1] + sb[2] + sb[3] + bq[r];
  } else if (id < 4096) {
    const int id2 = id - 3072;
    const int mat = id2 >> 9, i = id2 & 511;
    const float* W = mat ? tWp : sWp;
    const float* bo = mat ? t_bo : s_bo;
    const float* bp = mat ? t_bp : s_bp;
    float* o = mat ? bct : bcs;
    float dot = 0.0f;
    for (int j = threadIdx.x; j < 512; j += 256) dot += W[(long)i * 512 + j] * bo[j];
#pragma unroll
    for (int m = 32; m >= 1; m >>= 1) dot += __shfl_xor(dot, m, 64);
    if ((threadIdx.x & 63) == 0) sb[threadIdx.x >> 6] = dot;
    __syncthreads();
    if (threadIdx.x == 0) o[i] = sb[0] + sb[1] + sb[2] + sb[3] + bp[i];
  } else {
    const int idx = (id - 4096) * 256 + threadIdx.x;   // covers 512*2816 exactly
    const int r = idx / 2816, c = idx - r * 2816;
    Dout[idx] = (c < 2730) ? f2b(Wout[(long)r * 2730 + c]) : (u16)0;
  }
}

// ---------- t_ctx mean over tokens (direct, no atomics): grid (2, 4) ----------
__global__ __launch_bounds__(256) void pz_tmean2(const u16* __restrict__ T, float* __restrict__ O)
{
  const int b = blockIdx.y;
  const int col = blockIdx.x * 256 + threadIdx.x;
  const u16* base = T + (long)b * 512 * 512 + col;
  float s = 0.0f;
#pragma unroll 8
  for (int t = 0; t < 512; ++t) s += b2f(base[(long)t * 512]);
  O[b * 512 + col] = s * (1.0f / 512.0f);
}

// ---------- diagnostic fill ----------
__global__ void pz_diag(float* __restrict__ out, long n, float val)
{
  for (long i = (long)blockIdx.x * 256 + threadIdx.x; i < n; i += (long)gridDim.x * 256)
    out[i] = val;
}

// ---------- host ----------
extern "C" void kernel_launch(void* const* d_in, const int* in_sizes, int n_in,
                              void* d_out, int out_size, void* d_ws, size_t ws_size,
                              hipStream_t stream)
{
  (void)in_sizes; (void)n_in;
  const float* spat   = (const float*)d_in[0];
  const float* temp   = (const float*)d_in[1];
  const float* s_qg = (const float*)d_in[2],  * s_qb = (const float*)d_in[3];
  const float* s_kg = (const float*)d_in[4],  * s_kb = (const float*)d_in[5];
  const float* s_Wqkv = (const float*)d_in[6], * s_bqkv = (const float*)d_in[7];
  const float* s_Wo = (const float*)d_in[8],  * s_bo = (const float*)d_in[9];
  const float* s_Wp = (const float*)d_in[10], * s_bp = (const float*)d_in[11];
  const float* t_qg = (const float*)d_in[12], * t_qb = (const float*)d_in[13];
  const float* t_kg = (const float*)d_in[14], * t_kb = (const float*)d_in[15];
  const float* t_Wqkv = (const float*)d_in[16], * t_bqkv = (const float*)d_in[17];
  const float* t_Wo = (const float*)d_in[18], * t_bo = (const float*)d_in[19];
  const float* t_Wp = (const float*)d_in[20], * t_bp = (const float*)d_in[21];
  const float* mix_g = (const float*)d_in[22], * mix_b = (const float*)d_in[23];
  const float* mix_Win = (const float*)d_in[24], * mix_bin = (const float*)d_in[25];
  const float* mix_Wout = (const float*)d_in[26], * mix_bout = (const float*)d_in[27];
  float* out = (float*)d_out;

  char* ws = (char*)d_ws;
  size_t off = 0;
  auto take = [&](size_t n) { void* p = ws + off; off += (n + 255) & ~(size_t)255; return p; };

  u16* wA    = (u16*)take(1536L * 512 * 2);   // combined weights for nhat_s QKV gemm
  u16* wB    = (u16*)take(1536L * 512 * 2);   // combined weights for nhat_t QKV gemm
  u16* wc_s  = (u16*)take(512L * 512 * 2);    // wc_s/wc_t contiguous: Z=2 batched C
  u16* wc_t  = (u16*)take(512L * 512 * 2);
  u16* woutp = (u16*)take(512L * 2816 * 2);   // Wout zero-padded to K=2816
  float* bA  = (float*)take(1536L * 4);
  float* bB  = (float*)take(1536L * 4);
  float* bcs = (float*)take(512L * 4);
  float* bct = (float*)take(512L * 4);
  // A region: nhat -> ctx -> winb (mix phase)
  u16* nhat_s = (u16*)take(16384L * 512 * 2);
  u16* nhat_t = (u16*)take(2048L * 512 * 2);
  // B region: fused QKV outputs -> sctx/hbuf/tctx/tmean
  u16* qkv_s = (u16*)take(16384L * 1536 * 2);  // [spatial Q | temporal KV], ld 1536
  u16* qkv_t = (u16*)take(2048L * 1536 * 2);   // [temporal Q | spatial KV], ld 1536
  // S region: 23068672 B total (gchunk needs all of it in the fallback mix phase)
  char* Sreg = (char*)take(16777216 + 2097152 + 4194304);
  const size_t NEED = off;

  if (ws_size < NEED) {
    pz_diag<<<2048, 256, 0, stream>>>(out, (long)out_size, (float)(ws_size >> 20));
    return;
  }

  // optional big-G region past all small allocations (un-chunked mix MLP)
  u16* Gbig = (u16*)(ws + off);
  const bool bigG = (ws_size >= off + 16384UL * 2816 * 2);

  u16* wtT_all = (u16*)Sreg;                    // 2 x 512KB (precompute phase)
  u16* wpb_all = (u16*)(Sreg + 1048576);        // 2 x 512KB
  u16* vt_s = (u16*)Sreg;                       // spatial V^T, 2MB (attention phase)
  u16* vtc4 = (u16*)(Sreg + 2097152);           // temporal V^T all batches, 16MB
  u16* ctx_s = nhat_s;
  u16* ctx_t = nhat_t;
  u16* sctx  = qkv_s;                           // [16384][512] ld 512 (post-attention)
  u16* hbuf  = qkv_s + 16384L * 512;            // [16384][1024], 32MB (post-attention)
  u16* tctx  = qkv_t;                           // [2048][512] ld 512
  float* tmean = (float*)(qkv_t + 2048L * 512); // 8KB in dead qkv_t tail
  u16* gchunk = (u16*)Sreg;                     // 4096*2816*2 = 23068672 = full Sreg
  u16* winb   = (u16*)nhat_s;                   // 11.18MB in dead ctx_s region

  auto gemm = [&](const u16* A, const u16* B, const float* bias,
                  const u16* residB, const float* residF, u16* Cb, float* Cf,
                  int M, int N, int K, int ldA, int ldB, int ldC, int ldR,
                  long aSH, long bSH, long cSH, long rSH, int Z, float alpha) {
    dim3 g((N + 127) / 128, M / 128, Z);
    pz_gemm_bt<<<g, dim3(256), 0, stream>>>(A, B, bias, residB, residF, Cb, Cf,
        M, N, K, ldA, ldB, ldC, ldR, aSH, bSH, cSH, rSH, alpha);
  };

  // --- precompute (merged): fold Wqkv (combined routing) + fold bc + pad Wout ---
  pz_prep<<<9728, 256, 0, stream>>>(s_Wqkv, t_Wqkv, s_bqkv, t_bqkv,
      s_qg, s_qb, s_kg, s_kb, t_qg, t_qb, t_kg, t_kb, wA, wB, bA, bB,
      s_Wp, s_bo, s_bp, t_Wp, t_bo, t_bp, bcs, bct, mix_Wout, woutp);
  pz_transpose_f2b<<<dim3(8, 2, 8), 256, 0, stream>>>(s_Wo, t_Wo, wtT_all, 512, 512, 262144);
  pz_f2b2<<<2048, 256, 0, stream>>>(s_Wp, t_Wp, wpb_all, 512 * 512);
  gemm(wpb_all, wtT_all, nullptr, nullptr, nullptr, wc_s, nullptr,
       512, 512, 512, 512, 512, 512, 0, 262144, 262144, 262144, 0, 2, 1.0f);

  // --- LN (merged spatial + temporal) ---
  pz_ln2<<<18432, 256, 0, stream>>>(spat, temp, nhat_s, nhat_t, 16384);

  // --- QKV projections: ONE dual-job dispatch (spatial y<128, temporal y>=128) ---
  pz_gemm_bt2<<<dim3(12, 144), 256, 0, stream>>>(
      nhat_s, wA, bA, nullptr, nullptr, qkv_s, nullptr,
      16384, 1536, 512, 512, 512, 1536, 0, 1.0f,
      nhat_t, wB, bB, nullptr, nullptr, qkv_t, nullptr,
      2048,  1536, 512, 512, 512, 1536, 0, 1.0f, 128);

  // --- V^T transposes: ONE dual-job dispatch (x<8 spatial, x>=8 temporal) ---
  pz_transpose2<<<dim3(72, 4, 8), 256, 0, stream>>>(
      qkv_t, vt_s, 512, 1536, 1024, 512L * 1536, 8L * 64 * 512,
      qkv_s, vtc4, 4096, 1536, 1024, 4096L * 1536, 512L * 4096, 8);

  // --- fused attention: ONE dispatch (x<128 spatial tile, x>=128 temporal tile) ---
  pz_attn<<<dim3(144, 1, 32), 256, 0, stream>>>(
      qkv_s, qkv_t + 512, vt_s, ctx_s,
      qkv_t, qkv_s + 512, vtc4, ctx_t, 1536, 1536);

  // --- combined output projection: ONE dual-job dispatch ---
  pz_gemm_bt2<<<dim3(4, 144), 256, 0, stream>>>(
      ctx_s, wc_s, bcs, nullptr, spat, sctx, nullptr,
      16384, 512, 512, 512, 512, 512, 512, 1.0f,
      ctx_t, wc_t, bct, nullptr, temp, tctx, nullptr,
      2048,  512, 512, 512, 512, 512, 512, 1.0f, 128);

  // --- t_mean (direct reduction) + mix LN (+ mix_Win f2b fused tail) ---
  pz_tmean2<<<dim3(2, 4), 256, 0, stream>>>(tctx, tmean);
  pz_mix_ln_f2b<<<38224, 256, 0, stream>>>(sctx, tmean, mix_g, mix_b, hbuf,
      mix_Win, winb);

  // --- mix MLP: 3-buffer deep-pipelined uvgate, then direct Wout GEMM ---
  if (bigG) {
    pz_gemm_uvgate<<<dim3(44, 128), 256, 0, stream>>>(hbuf, winb, winb + 2730L * 1024,
        mix_bin, mix_bin + 2730, Gbig, 16384, 2730, 1024, 1024, 1024, 2816, 2816);
    gemm(Gbig, woutp, mix_bout, sctx, nullptr, nullptr, out,
         16384, 512, 2816, 2816, 2816, 512, 512, 0,0,0,0, 1, 1.0f);
  } else {
    for (int c = 0; c < 4; ++c) {
      const u16* Ah = hbuf + (long)c * 4096 * 1024;
      pz_gemm_uvgate<<<dim3(44, 32), 256, 0, stream>>>(Ah, winb, winb + 2730L * 1024,
          mix_bin, mix_bin + 2730, gchunk, 4096, 2730, 1024, 1024, 1024, 2816, 2816);
      gemm(gchunk, woutp, mix_bout, sctx + (long)c * 4096 * 512, nullptr, nullptr,
           out + (long)c * 4096 * 512,
           4096, 512, 2816, 2816, 2816, 512, 512, 0,0,0,0, 1, 1.0f);
    }
  }
}

// Round 12
// 793.966 us; speedup vs baseline: 1.0572x; 1.0572x over previous
//
#include <hip/hip_runtime.h>
#include <stdint.h>

typedef unsigned short u16;
typedef __bf16 bf16_t;
typedef bf16_t bf16x8 __attribute__((ext_vector_type(8)));
typedef float f32x4 __attribute__((ext_vector_type(4)));

// ---------- helpers ----------
__device__ __forceinline__ u16 f2b(float f) {
  union { float f; uint32_t u; } x; x.f = f;
  uint32_t r = x.u + 0x7fffu + ((x.u >> 16) & 1u);
  return (u16)(r >> 16);
}
__device__ __forceinline__ float b2f(u16 b) {
  union { uint32_t u; float f; } x; x.u = ((uint32_t)b) << 16;
  return x.f;
}

// async global->LDS, 16B per lane. LDS dest = wave-uniform base + lane*16.
__device__ __forceinline__ void async16(const void* g, void* l) {
  auto gp = reinterpret_cast<__attribute__((address_space(1))) unsigned int*>(
      reinterpret_cast<uintptr_t>(g));
  auto lp = reinterpret_cast<__attribute__((address_space(3))) unsigned int*>(
      reinterpret_cast<uintptr_t>(l));
  __builtin_amdgcn_global_load_lds(gp, lp, 16, 0, 0);
}

// ---------- generic bf16 MFMA GEMM, 3-buffer 2-deep prefetch, counted vmcnt ----------
// C = alpha*A(MxK)*B(NxK)^T + bias [+resid]. LDS 3 x (A 8KB @0 + B 8KB @8KB) = 48KB.
__global__ __launch_bounds__(256) void pz_gemm_bt(
    const u16* __restrict__ A, const u16* __restrict__ B,
    const float* __restrict__ bias,
    const u16* __restrict__ residB, const float* __restrict__ residF,
    u16* __restrict__ Cb, float* __restrict__ Cf,
    int M, int N, int K, int ldA, int ldB, int ldC, int ldR,
    long aSH, long bSH, long cSH, long rSH, float alpha)
{
  __shared__ __align__(16) u16 sAll[3 * 8192];   // 48 KB

  const int tid = threadIdx.x;
  const int wave = tid >> 6, lane = tid & 63;
  const int lr = lane & 15, lg = lane >> 4;
  const int wm = wave >> 1, wn = wave & 1;
  const int z = blockIdx.z;

  const u16* Ab = A + (long)z * aSH;
  const u16* Bb = B + (long)z * bSH;
  const int m0 = blockIdx.y * 128;
  const int n0 = blockIdx.x * 128;

  const int srow = tid >> 2;
  const int sgk = (tid & 3) ^ ((tid >> 3) & 3);
  int ar0 = m0 + srow;      if (ar0 > M - 1) ar0 = M - 1;
  int ar1 = m0 + 64 + srow; if (ar1 > M - 1) ar1 = M - 1;
  int br0 = n0 + srow;      if (br0 > N - 1) br0 = N - 1;
  int br1 = n0 + 64 + srow; if (br1 > N - 1) br1 = N - 1;
  const u16* aP0 = Ab + (long)ar0 * ldA + sgk * 8;
  const u16* aP1 = Ab + (long)ar1 * ldA + sgk * 8;
  const u16* bP0 = Bb + (long)br0 * ldB + sgk * 8;
  const u16* bP1 = Bb + (long)br1 * ldB + sgk * 8;

  auto stage = [&](int buf, int k0) {
    u16* p = sAll + buf * 8192;
    async16(aP0 + k0, p + wave * 512);
    async16(aP1 + k0, p + 2048 + wave * 512);
    async16(bP0 + k0, p + 4096 + wave * 512);
    async16(bP1 + k0, p + 6144 + wave * 512);
  };

  const int swz = (lr >> 1) & 3;
  int aoff[4], boff[4];
#pragma unroll
  for (int i = 0; i < 4; ++i) {
    aoff[i] = (wm * 64 + i * 16 + lr) * 32 + ((lg ^ swz) * 8);
    boff[i] = (wn * 64 + i * 16 + lr) * 32 + ((lg ^ swz) * 8);
  }

  f32x4 acc[4][4] = {};
  const int kiters = K >> 5;

  stage(0, 0);
  if (kiters > 1) stage(1, 32);

  int cur = 0;
  for (int kt = 0; kt < kiters; ++kt) {
    if (kt + 2 < kiters) {
      const int nx = (cur + 2 >= 3) ? cur - 1 : cur + 2;
      stage(nx, (kt + 2) << 5);
    }
    if (kt + 2 < kiters)      asm volatile("s_waitcnt vmcnt(8)" ::: "memory");
    else if (kt + 1 < kiters) asm volatile("s_waitcnt vmcnt(4)" ::: "memory");
    else                      asm volatile("s_waitcnt vmcnt(0)" ::: "memory");
    __builtin_amdgcn_s_barrier();
    asm volatile("" ::: "memory");

    const u16* base = sAll + cur * 8192;
    bf16x8 af[4], bfr[4];
#pragma unroll
    for (int i = 0; i < 4; ++i) af[i] = *(const bf16x8*)(base + aoff[i]);
#pragma unroll
    for (int i = 0; i < 4; ++i) bfr[i] = *(const bf16x8*)(base + 4096 + boff[i]);
#pragma unroll
    for (int i = 0; i < 4; ++i)
#pragma unroll
      for (int j = 0; j < 4; ++j)
        acc[i][j] = __builtin_amdgcn_mfma_f32_16x16x32_bf16(af[i], bfr[j], acc[i][j], 0, 0, 0);

    asm volatile("" ::: "memory");
    __builtin_amdgcn_s_barrier();
    cur = (cur + 1 == 3) ? 0 : cur + 1;
  }

  // C/D layout: col = lane&15, row = (lane>>4)*4 + reg  [m89/m91]
  const long coff = (long)z * cSH;
  const long roff = (long)z * rSH;
#pragma unroll
  for (int j = 0; j < 4; ++j) {
    const int n = n0 + wn * 64 + j * 16 + lr;
    if (n < N) {
      const float bv = bias ? bias[n] : 0.0f;
#pragma unroll
      for (int i = 0; i < 4; ++i) {
        const int mb = m0 + wm * 64 + i * 16 + lg * 4;
#pragma unroll
        for (int r = 0; r < 4; ++r) {
          const int m = mb + r;
          float v = alpha * acc[i][j][r] + bv;
          const long ri = roff + (long)m * ldR + n;
          if (residB) v += b2f(residB[ri]);
          if (residF) v += residF[ri];
          const long ci = coff + (long)m * ldC + n;
          if (Cb) Cb[ci] = f2b(v);
          if (Cf) Cf[ci] = v;
        }
      }
    }
  }
}

// ---------- fully fused spatial attention: QK^T + softmax + PV ----------
// grid (128, 1, 32): z -> (batch = z>>3, head = z&7).  Nk=512, D=64.
// ldQ/ldK parameterized (Q and K may live in wide fused-QKV buffers).
__global__ __launch_bounds__(256) void pz_sattn(
    const u16* __restrict__ Q, const u16* __restrict__ K,
    const u16* __restrict__ V, u16* __restrict__ O, int ldQ, int ldK)
{
  __shared__ __align__(16) u16 sQ[32 * 64];    // 4 KB
  __shared__ __align__(16) u16 sK[512 * 32];   // 32 KB; reused as P[32][512] after QK
  __shared__ float redm[32][4];
  __shared__ float reds[32][4];

  const int tid = threadIdx.x;
  const int wave = tid >> 6, lane = tid & 63;
  const int lr = lane & 15, lg = lane >> 4;
  const int z = blockIdx.z;
  const int b = z >> 3, h = z & 7;
  const int q0 = blockIdx.x * 32;

  const u16* Qb = Q + (long)b * 4096 * ldQ + h * 64;
  const u16* Kb = K + (long)b * 512 * ldK + h * 64;
  const u16* Vb = V + ((long)b * 8 + h) * (64L * 512);
  u16* Ob = O + (long)b * 4096 * 512 + h * 64;

  {
    const int qrow = wave * 8 + (lane >> 3);
    const int qcol = ((lane & 7) ^ (lane >> 3)) * 8;
    async16(Qb + (long)(q0 + qrow) * ldQ + qcol, sQ + wave * 512);
  }
  const int krow = wave * 16 + (lane >> 2);
  const int kcol = ((lane & 3) ^ ((lane >> 3) & 3)) * 8;
  const u16* kP = Kb + (long)krow * ldK + kcol;

  f32x4 acc[8][2] = {};
#pragma unroll
  for (int kk = 0; kk < 2; ++kk) {
    __syncthreads();
#pragma unroll
    for (int s = 0; s < 8; ++s)
      async16(kP + kk * 32 + (long)s * 64 * ldK, sK + s * 2048 + wave * 512);
    __builtin_amdgcn_s_waitcnt(0x0f70);
    __syncthreads();

    bf16x8 kf[8], qf[2];
#pragma unroll
    for (int kb = 0; kb < 8; ++kb) {
      const int n = wave * 128 + kb * 16 + lr;
      kf[kb] = *(const bf16x8*)(sK + n * 32 + ((lg ^ ((lr >> 1) & 3)) * 8));
    }
#pragma unroll
    for (int nq = 0; nq < 2; ++nq) {
      const int r = nq * 16 + lr;
      qf[nq] = *(const bf16x8*)(sQ + r * 64 + (((kk * 4 + lg) ^ (r & 7)) * 8));
    }
    __builtin_amdgcn_s_setprio(1);
#pragma unroll
    for (int kb = 0; kb < 8; ++kb)
#pragma unroll
      for (int nq = 0; nq < 2; ++nq)
        acc[kb][nq] = __builtin_amdgcn_mfma_f32_16x16x32_bf16(kf[kb], qf[nq], acc[kb][nq], 0, 0, 0);
    __builtin_amdgcn_s_setprio(0);
  }

  float mx0, mx1;
  {
    float m0 = acc[0][0][0], m1 = acc[0][1][0];
#pragma unroll
    for (int kb = 0; kb < 8; ++kb)
#pragma unroll
      for (int rg = 0; rg < 4; ++rg) {
        m0 = fmaxf(m0, acc[kb][0][rg]);
        m1 = fmaxf(m1, acc[kb][1][rg]);
      }
    m0 = fmaxf(m0, __shfl_xor(m0, 16, 64)); m0 = fmaxf(m0, __shfl_xor(m0, 32, 64));
    m1 = fmaxf(m1, __shfl_xor(m1, 16, 64)); m1 = fmaxf(m1, __shfl_xor(m1, 32, 64));
    mx0 = m0; mx1 = m1;
  }
  if (lane < 16) { redm[lr][wave] = mx0; redm[16 + lr][wave] = mx1; }
  __syncthreads();
  float inv[2];
#pragma unroll
  for (int nq = 0; nq < 2; ++nq) {
    const int q = nq * 16 + lr;
    const float m = fmaxf(fmaxf(redm[q][0], redm[q][1]), fmaxf(redm[q][2], redm[q][3]));
    float s = 0.0f;
#pragma unroll
    for (int kb = 0; kb < 8; ++kb)
#pragma unroll
      for (int rg = 0; rg < 4; ++rg) {
        const float e = __expf(0.125f * (acc[kb][nq][rg] - m));
        acc[kb][nq][rg] = e;
        s += e;
      }
    s += __shfl_xor(s, 16, 64);
    s += __shfl_xor(s, 32, 64);
    if (lane < 16) reds[q][wave] = s;
  }
  __syncthreads();
#pragma unroll
  for (int nq = 0; nq < 2; ++nq) {
    const int q = nq * 16 + lr;
    inv[nq] = 1.0f / (reds[q][0] + reds[q][1] + reds[q][2] + reds[q][3]);
  }

#pragma unroll
  for (int nq = 0; nq < 2; ++nq) {
    const int q = nq * 16 + lr;
#pragma unroll
    for (int kb = 0; kb < 8; ++kb) {
      ushort4 w;
      w.x = f2b(acc[kb][nq][0] * inv[nq]);
      w.y = f2b(acc[kb][nq][1] * inv[nq]);
      w.z = f2b(acc[kb][nq][2] * inv[nq]);
      w.w = f2b(acc[kb][nq][3] * inv[nq]);
      const int c16 = wave * 16 + kb * 2 + (lg >> 1);
      const int byteoff = q * 1024 + ((c16 ^ (q & 7)) * 16) + (lg & 1) * 8;
      *(ushort4*)((char*)sK + byteoff) = w;
    }
  }
  __syncthreads();

  const u16* vp = Vb + (long)(wave * 16 + lr) * 512;
  f32x4 opv[2] = {};
#pragma unroll
  for (int ks = 0; ks < 16; ++ks) {
    const bf16x8 bv = *(const bf16x8*)(vp + ks * 32 + lg * 8);
    bf16x8 pf[2];
#pragma unroll
    for (int mi = 0; mi < 2; ++mi) {
      const int r = mi * 16 + lr;
      pf[mi] = *(const bf16x8*)((char*)sK + r * 1024 + (((ks * 4 + lg) ^ (lr & 7)) * 16));
    }
    __builtin_amdgcn_s_setprio(1);
#pragma unroll
    for (int mi = 0; mi < 2; ++mi)
      opv[mi] = __builtin_amdgcn_mfma_f32_16x16x32_bf16(pf[mi], bv, opv[mi], 0, 0, 0);
    __builtin_amdgcn_s_setprio(0);
  }
#pragma unroll
  for (int mi = 0; mi < 2; ++mi)
#pragma unroll
    for (int rg = 0; rg < 4; ++rg) {
      const int q = q0 + mi * 16 + lg * 4 + rg;
      Ob[(long)q * 512 + wave * 16 + lr] = f2b(opv[mi][rg]);
    }
}

// ---------- fully fused temporal attention: flash-style over 8 key-tiles of 512 ----------
// grid (16, 1, 32): z -> (batch = z>>3, head = z&7). Nq=512/batch, Nk=4096, D=64.
__global__ __launch_bounds__(256) void pz_tattn(
    const u16* __restrict__ Q, const u16* __restrict__ K,
    const u16* __restrict__ VT,  // V^T  [4][512 d][4096 key]
    u16* __restrict__ O, int ldQ, int ldK)
{
  __shared__ __align__(16) u16 sQ[32 * 64];
  __shared__ __align__(16) u16 sK[512 * 32];   // K tile; reused as P[32][512] per tile
  __shared__ float redm[32][4];
  __shared__ float reds[32][4];
  __shared__ float m_run[32], l_run[32], alpha_sh[32];

  const int tid = threadIdx.x;
  const int wave = tid >> 6, lane = tid & 63;
  const int lr = lane & 15, lg = lane >> 4;
  const int z = blockIdx.z;
  const int b = z >> 3, h = z & 7;
  const int q0 = blockIdx.x * 32;

  const u16* Qb = Q + (long)b * 512 * ldQ + h * 64;
  const u16* Kb = K + (long)b * 4096 * ldK + h * 64;
  const u16* Vb = VT + (long)b * 512 * 4096 + (long)h * 64 * 4096;
  u16* Ob = O + (long)b * 512 * 512 + h * 64;

  if (tid < 32) { m_run[tid] = -3.0e38f; l_run[tid] = 0.0f; }

  {
    const int qrow = wave * 8 + (lane >> 3);
    const int qcol = ((lane & 7) ^ (lane >> 3)) * 8;
    async16(Qb + (long)(q0 + qrow) * ldQ + qcol, sQ + wave * 512);
  }
  const int krow = wave * 16 + (lane >> 2);
  const int kcol = ((lane & 3) ^ ((lane >> 3) & 3)) * 8;

  f32x4 opv[2] = {};

  for (int kt = 0; kt < 8; ++kt) {
    const u16* kP = Kb + ((long)kt * 512 + krow) * ldK + kcol;
    f32x4 acc[8][2] = {};
#pragma unroll
    for (int kk = 0; kk < 2; ++kk) {
      __syncthreads();   // protects sK rewrite vs previous tile's PV reads
#pragma unroll
      for (int s = 0; s < 8; ++s)
        async16(kP + kk * 32 + (long)s * 64 * ldK, sK + s * 2048 + wave * 512);
      __builtin_amdgcn_s_waitcnt(0x0f70);  // vmcnt(0)
      __syncthreads();

      bf16x8 kf[8], qf[2];
#pragma unroll
      for (int kb = 0; kb < 8; ++kb) {
        const int n = wave * 128 + kb * 16 + lr;
        kf[kb] = *(const bf16x8*)(sK + n * 32 + ((lg ^ ((lr >> 1) & 3)) * 8));
      }
#pragma unroll
      for (int nq = 0; nq < 2; ++nq) {
        const int r = nq * 16 + lr;
        qf[nq] = *(const bf16x8*)(sQ + r * 64 + (((kk * 4 + lg) ^ (r & 7)) * 8));
      }
      __builtin_amdgcn_s_setprio(1);
#pragma unroll
      for (int kb = 0; kb < 8; ++kb)
#pragma unroll
        for (int nq = 0; nq < 2; ++nq)
          acc[kb][nq] = __builtin_amdgcn_mfma_f32_16x16x32_bf16(kf[kb], qf[nq], acc[kb][nq], 0, 0, 0);
      __builtin_amdgcn_s_setprio(0);
    }

#pragma unroll
    for (int nq = 0; nq < 2; ++nq) {
      float m = acc[0][nq][0];
#pragma unroll
      for (int kb = 0; kb < 8; ++kb)
#pragma unroll
        for (int rg = 0; rg < 4; ++rg) m = fmaxf(m, acc[kb][nq][rg]);
      m = fmaxf(m, __shfl_xor(m, 16, 64));
      m = fmaxf(m, __shfl_xor(m, 32, 64));
      if (lane < 16) redm[nq * 16 + lr][wave] = m;
    }
    __syncthreads();

#pragma unroll
    for (int nq = 0; nq < 2; ++nq) {
      const int q = nq * 16 + lr;
      const float mt = fmaxf(fmaxf(redm[q][0], redm[q][1]), fmaxf(redm[q][2], redm[q][3]));
      const float mn = fmaxf(m_run[q], mt);
      float s = 0.0f;
#pragma unroll
      for (int kb = 0; kb < 8; ++kb)
#pragma unroll
        for (int rg = 0; rg < 4; ++rg) {
          const float e = __expf(0.125f * (acc[kb][nq][rg] - mn));
          acc[kb][nq][rg] = e;
          s += e;
        }
      s += __shfl_xor(s, 16, 64);
      s += __shfl_xor(s, 32, 64);
      if (lane < 16) reds[q][wave] = s;
    }
    __syncthreads();

    if (tid < 32) {
      const int q = tid;
      const float mt = fmaxf(fmaxf(redm[q][0], redm[q][1]), fmaxf(redm[q][2], redm[q][3]));
      const float mo = m_run[q];
      const float mn = fmaxf(mo, mt);
      const float al = __expf(0.125f * (mo - mn));
      l_run[q] = l_run[q] * al + (reds[q][0] + reds[q][1] + reds[q][2] + reds[q][3]);
      m_run[q] = mn;
      alpha_sh[q] = al;
    }
#pragma unroll
    for (int nq = 0; nq < 2; ++nq) {
      const int q = nq * 16 + lr;
#pragma unroll
      for (int kb = 0; kb < 8; ++kb) {
        ushort4 w;
        w.x = f2b(acc[kb][nq][0]);
        w.y = f2b(acc[kb][nq][1]);
        w.z = f2b(acc[kb][nq][2]);
        w.w = f2b(acc[kb][nq][3]);
        const int c16 = wave * 16 + kb * 2 + (lg >> 1);
        const int byteoff = q * 1024 + ((c16 ^ (q & 7)) * 16) + (lg & 1) * 8;
        *(ushort4*)((char*)sK + byteoff) = w;
      }
    }
    __syncthreads();

#pragma unroll
    for (int mi = 0; mi < 2; ++mi)
#pragma unroll
      for (int rg = 0; rg < 4; ++rg)
        opv[mi][rg] *= alpha_sh[mi * 16 + lg * 4 + rg];

    const u16* vp = Vb + (long)(wave * 16 + lr) * 4096 + kt * 512;
#pragma unroll
    for (int ks = 0; ks < 16; ++ks) {
      const bf16x8 bv = *(const bf16x8*)(vp + ks * 32 + lg * 8);
      bf16x8 pf[2];
#pragma unroll
      for (int mi = 0; mi < 2; ++mi) {
        const int r = mi * 16 + lr;
        pf[mi] = *(const bf16x8*)((char*)sK + r * 1024 + (((ks * 4 + lg) ^ (lr & 7)) * 16));
      }
      __builtin_amdgcn_s_setprio(1);
#pragma unroll
      for (int mi = 0; mi < 2; ++mi)
        opv[mi] = __builtin_amdgcn_mfma_f32_16x16x32_bf16(pf[mi], bv, opv[mi], 0, 0, 0);
      __builtin_amdgcn_s_setprio(0);
    }
  }

#pragma unroll
  for (int mi = 0; mi < 2; ++mi)
#pragma unroll
    for (int rg = 0; rg < 4; ++rg) {
      const int qr = mi * 16 + lg * 4 + rg;
      Ob[(long)(q0 + qr) * 512 + wave * 16 + lr] = f2b(opv[mi][rg] * (1.0f / l_run[qr]));
    }
}

// ---------- fused dual GEMM + SwiGLU gate, 3-buffer 2-deep prefetch, counted vmcnt ----------
// Tile 128(M) x 64(N); 4 waves each own a 64x32 quadrant of BOTH U and V.
__global__ __launch_bounds__(256) void pz_gemm_uvgate(
    const u16* __restrict__ A, const u16* __restrict__ Bu, const u16* __restrict__ Bv,
    const float* __restrict__ biasU, const float* __restrict__ biasV,
    u16* __restrict__ G, int M, int N, int K, int ldA, int ldB, int ldG, int Npad)
{
  __shared__ __align__(16) u16 sAll[3 * 8192];   // 48 KB

  const int tid = threadIdx.x;
  const int wave = tid >> 6, lane = tid & 63;
  const int lr = lane & 15, lg = lane >> 4;
  const int wm = wave >> 1, wn = wave & 1;
  const int m0 = blockIdx.y * 128;
  const int n0 = blockIdx.x * 64;

  const int srow = tid >> 2;                      // 0..63
  const int sgk = (tid & 3) ^ ((tid >> 3) & 3);
  int ar0 = m0 + srow;      if (ar0 > M - 1) ar0 = M - 1;
  int ar1 = m0 + 64 + srow; if (ar1 > M - 1) ar1 = M - 1;
  int br  = n0 + srow;      if (br  > N - 1) br  = N - 1;
  const u16* aP0 = A + (long)ar0 * ldA + sgk * 8;
  const u16* aP1 = A + (long)ar1 * ldA + sgk * 8;
  const u16* uP  = Bu + (long)br * ldB + sgk * 8;
  const u16* vP  = Bv + (long)br * ldB + sgk * 8;

  auto stage = [&](int buf, int k0) {
    u16* b = sAll + buf * 8192;
    async16(aP0 + k0, b + wave * 512);
    async16(aP1 + k0, b + 2048 + wave * 512);
    async16(uP + k0, b + 4096 + wave * 512);
    async16(vP + k0, b + 6144 + wave * 512);
  };

  const int swz = (lr >> 1) & 3;
  int aoff[4], boff[2];
#pragma unroll
  for (int i = 0; i < 4; ++i) aoff[i] = (wm * 64 + i * 16 + lr) * 32 + ((lg ^ swz) * 8);
#pragma unroll
  for (int j = 0; j < 2; ++j) boff[j] = (wn * 32 + j * 16 + lr) * 32 + ((lg ^ swz) * 8);

  f32x4 aU[4][2] = {}, aV[4][2] = {};
  const int kiters = K >> 5;

  // prologue: 2 tiles in flight (8 outstanding loads/wave)
  stage(0, 0);
  if (kiters > 1) stage(1, 32);

  int cur = 0;
  for (int kt = 0; kt < kiters; ++kt) {
    if (kt + 2 < kiters) {
      const int nx = (cur + 2 >= 3) ? cur - 1 : cur + 2;
      stage(nx, (kt + 2) << 5);
    }
    if (kt + 2 < kiters)      asm volatile("s_waitcnt vmcnt(8)" ::: "memory");
    else if (kt + 1 < kiters) asm volatile("s_waitcnt vmcnt(4)" ::: "memory");
    else                      asm volatile("s_waitcnt vmcnt(0)" ::: "memory");
    __builtin_amdgcn_s_barrier();            // all waves' tile-kt data visible
    asm volatile("" ::: "memory");

    const u16* base = sAll + cur * 8192;
    bf16x8 af[4], uf[2], vf[2];
#pragma unroll
    for (int i = 0; i < 4; ++i) af[i] = *(const bf16x8*)(base + aoff[i]);
#pragma unroll
    for (int j = 0; j < 2; ++j) uf[j] = *(const bf16x8*)(base + 4096 + boff[j]);
#pragma unroll
    for (int j = 0; j < 2; ++j) vf[j] = *(const bf16x8*)(base + 6144 + boff[j]);
#pragma unroll
    for (int i = 0; i < 4; ++i)
#pragma unroll
      for (int j = 0; j < 2; ++j) {
        aU[i][j] = __builtin_amdgcn_mfma_f32_16x16x32_bf16(af[i], uf[j], aU[i][j], 0, 0, 0);
        aV[i][j] = __builtin_amdgcn_mfma_f32_16x16x32_bf16(af[i], vf[j], aV[i][j], 0, 0, 0);
      }

    asm volatile("" ::: "memory");
    __builtin_amdgcn_s_barrier();            // all waves done reading buf cur
    cur = (cur + 1 == 3) ? 0 : cur + 1;
  }

#pragma unroll
  for (int j = 0; j < 2; ++j) {
    const int n = n0 + wn * 32 + j * 16 + lr;
    if (n < N) {
      const float bu = biasU[n], bv = biasV[n];
#pragma unroll
      for (int i = 0; i < 4; ++i) {
        const int mb = m0 + wm * 64 + i * 16 + lg * 4;
#pragma unroll
        for (int r = 0; r < 4; ++r) {
          const float u = aU[i][j][r] + bu;
          const float v = aV[i][j][r] + bv;
          G[(long)(mb + r) * ldG + n] = f2b((u / (1.0f + __expf(-u))) * v);
        }
      }
    } else if (n < Npad) {
#pragma unroll
      for (int i = 0; i < 4; ++i) {
        const int mb = m0 + wm * 64 + i * 16 + lg * 4;
#pragma unroll
        for (int r = 0; r < 4; ++r) G[(long)(mb + r) * ldG + n] = 0;
      }
    }
  }
}

// ---------- merged LN (spatial + temporal): rows [0,split) from X0, rest X1 ----------
__global__ __launch_bounds__(256) void pz_ln2(
    const float* __restrict__ X0, const float* __restrict__ X1,
    u16* __restrict__ O0, u16* __restrict__ O1, int split)
{
  __shared__ float sm[4], sq[4];
  const int tid = threadIdx.x;
  const long row = blockIdx.x;
  const float* x;
  u16* O;
  if (row < split) { x = X0 + row * 512; O = O0 + row * 512; }
  else             { const long r2 = row - split; x = X1 + r2 * 512; O = O1 + r2 * 512; }
  float a = x[tid], b = x[tid + 256];
  float s = a + b, q = a * a + b * b;
#pragma unroll
  for (int m = 32; m >= 1; m >>= 1) { s += __shfl_xor(s, m, 64); q += __shfl_xor(q, m, 64); }
  if ((tid & 63) == 0) { sm[tid >> 6] = s; sq[tid >> 6] = q; }
  __syncthreads();
  s = sm[0] + sm[1] + sm[2] + sm[3];
  q = sq[0] + sq[1] + sq[2] + sq[3];
  const float mean = s * (1.0f / 512.0f);
  const float rstd = rsqrtf(q * (1.0f / 512.0f) - mean * mean + 1e-5f);
  O[tid]       = f2b((a - mean) * rstd);
  O[tid + 256] = f2b((b - mean) * rstd);
}

// ---------- mix LN over concat(sctx[512] bf16, tmean[512] f32) + mix_Win f2b tail ----------
// grid: [0,16384) mix-LN rows; [16384, 16384+21840) convert mix_Win (5460*1024 f32 -> bf16)
__global__ __launch_bounds__(256) void pz_mix_ln_f2b(
    const u16* __restrict__ SC, const float* __restrict__ TM,
    const float* __restrict__ g, const float* __restrict__ b, u16* __restrict__ H,
    const float* __restrict__ Wsrc, u16* __restrict__ Wdst)
{
  __shared__ float sm[4], sq[4];
  const int tid = threadIdx.x;
  if (blockIdx.x >= 16384) {
    const int i = (blockIdx.x - 16384) * 256 + tid;  // covers 5460*1024 exactly
    Wdst[i] = f2b(Wsrc[i]);
    return;
  }
  const long row = blockIdx.x;
  const int bb = (int)(row >> 12);
  const u16* x0 = SC + row * 512;
  const float* x1 = TM + (long)bb * 512;
  float v0 = b2f(x0[tid]), v1 = b2f(x0[tid + 256]);
  float v2 = x1[tid], v3 = x1[tid + 256];
  float s = v0 + v1 + v2 + v3;
  float q = v0 * v0 + v1 * v1 + v2 * v2 + v3 * v3;
#pragma unroll
  for (int m = 32; m >= 1; m >>= 1) { s += __shfl_xor(s, m, 64); q += __shfl_xor(q, m, 64); }
  if ((tid & 63) == 0) { sm[tid >> 6] = s; sq[tid >> 6] = q; }
  __syncthreads();
  s = sm[0] + sm[1] + sm[2] + sm[3];
  q = sq[0] + sq[1] + sq[2] + sq[3];
  const float mean = s * (1.0f / 1024.0f);
  const float rstd = rsqrtf(q * (1.0f / 1024.0f) - mean * mean + 1e-5f);
  u16* hr = H + row * 1024;
  hr[tid]       = f2b((v0 - mean) * rstd * g[tid]       + b[tid]);
  hr[tid + 256] = f2b((v1 - mean) * rstd * g[tid + 256] + b[tid + 256]);
  hr[tid + 512] = f2b((v2 - mean) * rstd * g[tid + 512] + b[tid + 512]);
  hr[tid + 768] = f2b((v3 - mean) * rstd * g[tid + 768] + b[tid + 768]);
}

// ---------- bf16 slice transpose (batched via blockIdx.y) ----------
__global__ __launch_bounds__(256) void pz_transpose(
    const u16* __restrict__ S, u16* __restrict__ D, int Nk, int ldS, int colBase,
    long sBS, long dBS)
{
  __shared__ u16 t[64][65];
  const int z = blockIdx.z;
  const int nk0 = blockIdx.x * 64;
  const int tid = threadIdx.x;
  S += (long)blockIdx.y * sBS;
  D += (long)blockIdx.y * dBS;
  for (int i = tid; i < 4096; i += 256) {
    int r = i >> 6, d = i & 63;
    t[r][d] = S[(long)(nk0 + r) * ldS + colBase + z * 64 + d];
  }
  __syncthreads();
  for (int i = tid; i < 4096; i += 256) {
    int d = i >> 6, c = i & 63;
    D[((long)z * 64 + d) * Nk + nk0 + c] = t[c][d];
  }
}

// ---------- f32 transpose + convert to bf16, batched over two sources (Wo^T s/t) ----------
__global__ __launch_bounds__(256) void pz_transpose_f2b(
    const float* __restrict__ S0, const float* __restrict__ S1,
    u16* __restrict__ D, int Nk, int ldS, long dBS)
{
  __shared__ u16 t[64][65];
  const float* S = blockIdx.y ? S1 : S0;
  D += (long)blockIdx.y * dBS;
  const int z = blockIdx.z;
  const int nk0 = blockIdx.x * 64;
  const int tid = threadIdx.x;
  for (int i = tid; i < 4096; i += 256) {
    int r = i >> 6, d = i & 63;
    t[r][d] = f2b(S[(long)(nk0 + r) * ldS + z * 64 + d]);
  }
  __syncthreads();
  for (int i = tid; i < 4096; i += 256) {
    int d = i >> 6, c = i & 63;
    D[((long)z * 64 + d) * Nk + nk0 + c] = t[c][d];
  }
}

// ---------- f32 -> bf16 convert, two sources into one contiguous dest ----------
__global__ __launch_bounds__(256) void pz_f2b2(
    const float* __restrict__ s0, const float* __restrict__ s1, u16* __restrict__ d, int n)
{
  const int i = blockIdx.x * 256 + threadIdx.x;   // grid covers 2n exactly
  d[i] = (i < n) ? f2b(s0[i]) : f2b(s1[i - n]);
}

// ---------- merged precompute: fold Wqkv (id<3072) | fold bc (id<4096) | pad Wout ----------
// Folded QKV rows routed into COMBINED buffers for the merged-by-A QKV gemms:
//   wA (for nhat_s): rows 0:512 = s_Wqkv Q-part;  rows 512:1536 = t_Wqkv KV-part
//   wB (for nhat_t): rows 0:512 = t_Wqkv Q-part;  rows 512:1536 = s_Wqkv KV-part
__global__ __launch_bounds__(256) void pz_prep(
    const float* __restrict__ Ws, const float* __restrict__ Wt,
    const float* __restrict__ bs, const float* __restrict__ bt,
    const float* s_qg, const float* s_qb, const float* s_kg, const float* s_kb,
    const float* t_qg, const float* t_qb, const float* t_kg, const float* t_kb,
    u16* __restrict__ wA, u16* __restrict__ wB, float* bA, float* bB,
    const float* sWp, const float* s_bo, const float* s_bp,
    const float* tWp, const float* t_bo, const float* t_bp, float* bcs, float* bct,
    const float* __restrict__ Wout, u16* __restrict__ Dout)
{
  __shared__ float sb[4];
  const int id = blockIdx.x;
  if (id < 3072) {
    const int mat = (id >= 1536) ? 1 : 0;
    const int r = id - mat * 1536;
    const float* W = mat ? Wt : Ws;
    const float* bq = mat ? bt : bs;
    const float *g, *bl;
    if (!mat) { g = (r < 512) ? s_qg : s_kg; bl = (r < 512) ? s_qb : s_kb; }
    else      { g = (r < 512) ? t_qg : t_kg; bl = (r < 512) ? t_qb : t_kb; }
    const bool toA = (mat == 0) == (r < 512);
    u16* Wo_ = toA ? wA : wB;
    float* bo_ = toA ? bA : bB;
    float dot = 0.0f;
    for (int c = threadIdx.x; c < 512; c += 256) {
      float w = W[(long)r * 512 + c];
      Wo_[(long)r * 512 + c] = f2b(w * g[c]);
      dot += w * bl[c];
    }
#pragma unroll
    for (int m = 32; m >= 1; m >>= 1) dot += __shfl_xor(dot, m, 64);
    if ((threadIdx.x & 63) == 0) sb[threadIdx.x >> 6] = dot;
    __syncthreads();
    if (threadIdx.x == 0) bo_[r] = sb[0] + sb[1] + sb[2] + sb[3] + bq[r];
  } else if (id < 4096) {
    const int id2 = id - 3072;
    const int mat = id2 >> 9, i = id2 & 511;
    const float* W = mat ? tWp : sWp;
    const float* bo = mat ? t_bo : s_bo;
    const float* bp = mat ? t_bp : s_bp;
    float* o = mat ? bct : bcs;
    float dot = 0.0f;
    for (int j = threadIdx.x; j < 512; j += 256) dot += W[(long)i * 512 + j] * bo[j];
#pragma unroll
    for (int m = 32; m >= 1; m >>= 1) dot += __shfl_xor(dot, m, 64);
    if ((threadIdx.x & 63) == 0) sb[threadIdx.x >> 6] = dot;
    __syncthreads();
    if (threadIdx.x == 0) o[i] = sb[0] + sb[1] + sb[2] + sb[3] + bp[i];
  } else {
    const int idx = (id - 4096) * 256 + threadIdx.x;   // covers 512*2816 exactly
    const int r = idx / 2816, c = idx - r * 2816;
    Dout[idx] = (c < 2730) ? f2b(Wout[(long)r * 2730 + c]) : (u16)0;
  }
}

// ---------- t_ctx mean over tokens ----------
__global__ __launch_bounds__(256) void pz_tmean(const u16* __restrict__ T, float* __restrict__ O)
{
  const int b = blockIdx.y, tc = blockIdx.x, tid = threadIdx.x;
  const u16* base = T + (long)b * 512 * 512 + (long)tc * 32 * 512;
  float s0 = 0.0f, s1 = 0.0f;
#pragma unroll 4
  for (int t = 0; t < 32; ++t) { s0 += b2f(base[t * 512 + tid]); s1 += b2f(base[t * 512 + tid + 256]); }
  atomicAdd(&O[b * 512 + tid],       s0 * (1.0f / 512.0f));
  atomicAdd(&O[b * 512 + tid + 256], s1 * (1.0f / 512.0f));
}

// ---------- diagnostic fill ----------
__global__ void pz_diag(float* __restrict__ out, long n, float val)
{
  for (long i = (long)blockIdx.x * 256 + threadIdx.x; i < n; i += (long)gridDim.x * 256)
    out[i] = val;
}

// ---------- host ----------
extern "C" void kernel_launch(void* const* d_in, const int* in_sizes, int n_in,
                              void* d_out, int out_size, void* d_ws, size_t ws_size,
                              hipStream_t stream)
{
  (void)in_sizes; (void)n_in;
  const float* spat   = (const float*)d_in[0];
  const float* temp   = (const float*)d_in[1];
  const float* s_qg = (const float*)d_in[2],  * s_qb = (const float*)d_in[3];
  const float* s_kg = (const float*)d_in[4],  * s_kb = (const float*)d_in[5];
  const float* s_Wqkv = (const float*)d_in[6], * s_bqkv = (const float*)d_in[7];
  const float* s_Wo = (const float*)d_in[8],  * s_bo = (const float*)d_in[9];
  const float* s_Wp = (const float*)d_in[10], * s_bp = (const float*)d_in[11];
  const float* t_qg = (const float*)d_in[12], * t_qb = (const float*)d_in[13];
  const float* t_kg = (const float*)d_in[14], * t_kb = (const float*)d_in[15];
  const float* t_Wqkv = (const float*)d_in[16], * t_bqkv = (const float*)d_in[17];
  const float* t_Wo = (const float*)d_in[18], * t_bo = (const float*)d_in[19];
  const float* t_Wp = (const float*)d_in[20], * t_bp = (const float*)d_in[21];
  const float* mix_g = (const float*)d_in[22], * mix_b = (const float*)d_in[23];
  const float* mix_Win = (const float*)d_in[24], * mix_bin = (const float*)d_in[25];
  const float* mix_Wout = (const float*)d_in[26], * mix_bout = (const float*)d_in[27];
  float* out = (float*)d_out;

  char* ws = (char*)d_ws;
  size_t off = 0;
  auto take = [&](size_t n) { void* p = ws + off; off += (n + 255) & ~(size_t)255; return p; };

  u16* wA    = (u16*)take(1536L * 512 * 2);   // combined weights for nhat_s QKV gemm
  u16* wB    = (u16*)take(1536L * 512 * 2);   // combined weights for nhat_t QKV gemm
  u16* wc_s  = (u16*)take(512L * 512 * 2);    // wc_s/wc_t contiguous: Z=2 batched C
  u16* wc_t  = (u16*)take(512L * 512 * 2);
  u16* woutp = (u16*)take(512L * 2816 * 2);   // Wout zero-padded to K=2816
  float* bA  = (float*)take(1536L * 4);
  float* bB  = (float*)take(1536L * 4);
  float* bcs = (float*)take(512L * 4);
  float* bct = (float*)take(512L * 4);
  // A region: nhat -> ctx -> winb (mix phase)
  u16* nhat_s = (u16*)take(16384L * 512 * 2);
  u16* nhat_t = (u16*)take(2048L * 512 * 2);
  // B region: fused QKV outputs -> sctx/hbuf/tctx/tmean
  u16* qkv_s = (u16*)take(16384L * 1536 * 2);  // [spatial Q | temporal KV], ld 1536
  u16* qkv_t = (u16*)take(2048L * 1536 * 2);   // [temporal Q | spatial KV], ld 1536
  // S region: 23068672 B total (gchunk needs all of it in the fallback mix phase)
  char* Sreg = (char*)take(16777216 + 2097152 + 4194304);
  const size_t NEED = off;

  if (ws_size < NEED) {
    pz_diag<<<2048, 256, 0, stream>>>(out, (long)out_size, (float)(ws_size >> 20));
    return;
  }

  // optional big-G region past all small allocations (un-chunked mix MLP)
  u16* Gbig = (u16*)(ws + off);
  const bool bigG = (ws_size >= off + 16384UL * 2816 * 2);

  u16* wtT_all = (u16*)Sreg;                    // 2 x 512KB (precompute phase)
  u16* wpb_all = (u16*)(Sreg + 1048576);        // 2 x 512KB
  u16* vt_s = (u16*)Sreg;                       // spatial V^T, 2MB (attention phase)
  u16* vtc4 = (u16*)(Sreg + 2097152);           // temporal V^T all batches, 16MB
  u16* ctx_s = nhat_s;
  u16* ctx_t = nhat_t;
  u16* sctx  = qkv_s;                           // [16384][512] ld 512 (post-attention)
  u16* hbuf  = qkv_s + 16384L * 512;            // [16384][1024], 32MB (post-attention)
  u16* tctx  = qkv_t;                           // [2048][512] ld 512
  float* tmean = (float*)(qkv_t + 2048L * 512); // 8KB in dead qkv_t tail
  u16* gchunk = (u16*)Sreg;                     // 4096*2816*2 = 23068672 = full Sreg
  u16* winb   = (u16*)nhat_s;                   // 11.18MB in dead ctx_s region

  auto gemm = [&](const u16* A, const u16* B, const float* bias,
                  const u16* residB, const float* residF, u16* Cb, float* Cf,
                  int M, int N, int K, int ldA, int ldB, int ldC, int ldR,
                  long aSH, long bSH, long cSH, long rSH, int Z, float alpha) {
    dim3 g((N + 127) / 128, M / 128, Z);
    pz_gemm_bt<<<g, dim3(256), 0, stream>>>(A, B, bias, residB, residF, Cb, Cf,
        M, N, K, ldA, ldB, ldC, ldR, aSH, bSH, cSH, rSH, alpha);
  };

  // --- precompute (merged): fold Wqkv (combined routing) + fold bc + pad Wout ---
  pz_prep<<<9728, 256, 0, stream>>>(s_Wqkv, t_Wqkv, s_bqkv, t_bqkv,
      s_qg, s_qb, s_kg, s_kb, t_qg, t_qb, t_kg, t_kb, wA, wB, bA, bB,
      s_Wp, s_bo, s_bp, t_Wp, t_bo, t_bp, bcs, bct, mix_Wout, woutp);
  pz_transpose_f2b<<<dim3(8, 2, 8), 256, 0, stream>>>(s_Wo, t_Wo, wtT_all, 512, 512, 262144);
  pz_f2b2<<<2048, 256, 0, stream>>>(s_Wp, t_Wp, wpb_all, 512 * 512);
  gemm(wpb_all, wtT_all, nullptr, nullptr, nullptr, wc_s, nullptr,
       512, 512, 512, 512, 512, 512, 0, 262144, 262144, 262144, 0, 2, 1.0f);

  // --- LN (merged spatial + temporal) ---
  pz_ln2<<<18432, 256, 0, stream>>>(spat, temp, nhat_s, nhat_t, 16384);

  // --- QKV projections, merged by A-operand: 2 gemms instead of 4 ---
  gemm(nhat_s, wA, bA, nullptr, nullptr, qkv_s, nullptr,
       16384, 1536, 512, 512, 512, 1536, 0, 0,0,0,0, 1, 1.0f);
  gemm(nhat_t, wB, bB, nullptr, nullptr, qkv_t, nullptr,
       2048,  1536, 512, 512, 512, 1536, 0, 0,0,0,0, 1, 1.0f);

  // --- V^T transposes (spatial V in qkv_t cols 1024:1536; temporal V in qkv_s) ---
  pz_transpose<<<dim3(8, 4, 8), 256, 0, stream>>>(qkv_t, vt_s, 512, 1536, 1024,
      512L * 1536, 8L * 64 * 512);
  pz_transpose<<<dim3(64, 4, 8), 256, 0, stream>>>(qkv_s, vtc4, 4096, 1536, 1024,
      4096L * 1536, 512L * 4096);

  // --- fused attention: spatial + temporal flash ---
  pz_sattn<<<dim3(128, 1, 32), 256, 0, stream>>>(qkv_s, qkv_t + 512, vt_s, ctx_s, 1536, 1536);
  pz_tattn<<<dim3(16, 1, 32), 256, 0, stream>>>(qkv_t, qkv_s + 512, vtc4, ctx_t, 1536, 1536);

  // --- combined output projection (Wc = Wp.Wo) + f32 residual -> bf16 ctx ---
  gemm(ctx_s, wc_s, bcs, nullptr, spat, sctx, nullptr,
       16384, 512, 512, 512, 512, 512, 512, 0,0,0,0, 1, 1.0f);
  gemm(ctx_t, wc_t, bct, nullptr, temp, tctx, nullptr,
       2048,  512, 512, 512, 512, 512, 512, 0,0,0,0, 1, 1.0f);

  // --- t_mean + mix LN (+ mix_Win f2b fused tail; winb region dead now) ---
  (void)hipMemsetAsync(tmean, 0, 4L * 512 * sizeof(float), stream);
  pz_tmean<<<dim3(16, 4), 256, 0, stream>>>(tctx, tmean);
  pz_mix_ln_f2b<<<38224, 256, 0, stream>>>(sctx, tmean, mix_g, mix_b, hbuf,
      mix_Win, winb);

  // --- mix MLP: 3-buffer deep-pipelined uvgate, then direct Wout GEMM ---
  if (bigG) {
    pz_gemm_uvgate<<<dim3(44, 128), 256, 0, stream>>>(hbuf, winb, winb + 2730L * 1024,
        mix_bin, mix_bin + 2730, Gbig, 16384, 2730, 1024, 1024, 1024, 2816, 2816);
    gemm(Gbig, woutp, mix_bout, sctx, nullptr, nullptr, out,
         16384, 512, 2816, 2816, 2816, 512, 512, 0,0,0,0, 1, 1.0f);
  } else {
    for (int c = 0; c < 4; ++c) {
      const u16* Ah = hbuf + (long)c * 4096 * 1024;
      pz_gemm_uvgate<<<dim3(44, 32), 256, 0, stream>>>(Ah, winb, winb + 2730L * 1024,
          mix_bin, mix_bin + 2730, gchunk, 4096, 2730, 1024, 1024, 1024, 2816, 2816);
      gemm(gchunk, woutp, mix_bout, sctx + (long)c * 4096 * 512, nullptr, nullptr,
           out + (long)c * 4096 * 512,
           4096, 512, 2816, 2816, 2816, 512, 512, 0,0,0,0, 1, 1.0f);
    }
  }
}